// Round 3
// baseline (471.680 us; speedup 1.0000x reference)
//
#include <hip/hip_runtime.h>
#include <stdint.h>

#define B_SZ 4096
#define K_SZ 4
#define D_SZ 1024
#define INV_T 14.285714285714286f   // 1/0.07
#define FP8_SCALE 16.0f             // input pre-scale; compensated by E8M0=123
#define E8M0_S 123                  // 2^(123-127) = 1/16 per operand

typedef __attribute__((ext_vector_type(8)))  int   i32x8_t;   // 32 fp8 bytes
typedef __attribute__((ext_vector_type(16))) float f32x16_t;  // 32x32 acc
typedef __attribute__((ext_vector_type(8)))  short bf16x8_t;
typedef __attribute__((ext_vector_type(4)))  float f32x4_t;
typedef unsigned short u16;

static __device__ __forceinline__ u16 f2bf(float f) {
    union { float f; uint32_t u; } v; v.f = f;
    return (u16)(v.u >> 16);
}

// async global->LDS, 16 bytes per lane; dest must be wave-uniform base + lane*16
static __device__ __forceinline__ void gl_lds16(const void* g, void* l) {
    __builtin_amdgcn_global_load_lds(
        (const __attribute__((address_space(1))) void*)g,
        (__attribute__((address_space(3))) void*)l, 16, 0, 0);
}

// ===========================================================================
// MAIN PATH: fp32 -> fp8(e4m3, x16) convert + diag dots, then one fused
// MX-scaled MFMA GEMM  W = txt . [img ; oth]^T  (4096 x 20480).
// ===========================================================================

// ---------------------------------------------------------------------------
// Pass 1: convert + diagonal dots. One 256-thread block per 1024-elem row.
// rows 0..4095: img (dot txt_r) | 4096..8191: txt | 8192..24575: oth (dot txt_{r>>2})
// ---------------------------------------------------------------------------
__global__ __launch_bounds__(256) void convert_diag_f8(
    const float* __restrict__ img, const float* __restrict__ txt,
    const float* __restrict__ other,
    uint8_t* __restrict__ img_f8, uint8_t* __restrict__ txt_f8,
    uint8_t* __restrict__ oth_f8, float* __restrict__ partials)
{
    const int row = blockIdx.x;
    const int t   = threadIdx.x;

    const float* src;
    const float* dotsrc = nullptr;
    uint8_t* dst;
    float* part = nullptr;

    if (row < B_SZ) {
        src    = img + (size_t)row * D_SZ;
        dst    = img_f8 + (size_t)row * D_SZ;
        dotsrc = txt + (size_t)row * D_SZ;
        part   = partials + row;
    } else if (row < 2 * B_SZ) {
        const int r = row - B_SZ;
        src = txt + (size_t)r * D_SZ;
        dst = txt_f8 + (size_t)r * D_SZ;
    } else {
        const int r = row - 2 * B_SZ;
        src    = other + (size_t)r * D_SZ;
        dst    = oth_f8 + (size_t)r * D_SZ;
        dotsrc = txt + (size_t)(r >> 2) * D_SZ;
        part   = partials + B_SZ + r;
    }

    float4 a = ((const float4*)src)[t];
    int p = __builtin_amdgcn_cvt_pk_fp8_f32(a.x * FP8_SCALE, a.y * FP8_SCALE, 0, false);
    p     = __builtin_amdgcn_cvt_pk_fp8_f32(a.z * FP8_SCALE, a.w * FP8_SCALE, p, true);
    ((int*)dst)[t] = p;

    if (part) {
        float4 b = ((const float4*)dotsrc)[t];
        float s = a.x * b.x + a.y * b.y + a.z * b.z + a.w * b.w;
#pragma unroll
        for (int d = 1; d < 64; d <<= 1) s += __shfl_xor(s, d);
        __shared__ float red[4];
        const int w = t >> 6, lane = t & 63;
        if (lane == 0) red[w] = s;
        __syncthreads();
        if (t == 0)
            part[0] = (red[0] + red[1] + red[2] + red[3]) * INV_T;
    }
}

// ---------------------------------------------------------------------------
// Pass 2: fused MX-fp8 GEMM+expsum. Tile 128x128, BK=64 (one MX block/lane).
// 4 waves, each a 64x64 quadrant of 2x2 32x32x64 MFMAs.
// LDS: linear slot t*16 holds global (row=t>>2, seg=(t&3)^(row&3)) -- XOR
// swizzle breaks the stride-64B bank pattern while keeping the
// global_load_lds wave-uniform-base+lane*16 dest identity.
// Epilogue: n0<4096 block => W = Q1^T: rowsum->cs1, colsum->rs1;
//           n0>=4096     => Q2: rowsum->rs2.
// ---------------------------------------------------------------------------
__global__ __launch_bounds__(256) void gemm_expsum_mx(
    const uint8_t* __restrict__ txt_f8, const uint8_t* __restrict__ img_f8,
    const uint8_t* __restrict__ oth_f8,
    float* __restrict__ rs1, float* __restrict__ cs1, float* __restrict__ rs2)
{
    __shared__ uint8_t lds_buf[16384];
    uint8_t* As = lds_buf;          // [128][64]
    uint8_t* Bs = lds_buf + 8192;   // [128][64]

    const int m0   = blockIdx.y * 128;            // txt rows
    const int n0   = blockIdx.x * 128;            // 0..20479
    const bool q1  = (n0 < B_SZ);
    const uint8_t* Ybase = q1 ? (img_f8 + (size_t)n0 * D_SZ)
                              : (oth_f8 + (size_t)(n0 - B_SZ) * D_SZ);

    const int tid  = threadIdx.x;
    const int lane = tid & 63;
    const int w    = tid >> 6;
    const int wm   = (w & 1) * 64;
    const int wn   = (w >> 1) * 64;
    const int l31  = lane & 31;
    const int kh   = lane >> 5;       // k-half (0/1) for 32-elem blocks
    const int r3   = lane & 3;        // row&3 of every frag row this lane reads

    f32x16_t acc[2][2];
#pragma unroll
    for (int i = 0; i < 2; i++)
#pragma unroll
        for (int j = 0; j < 2; j++)
#pragma unroll
            for (int r = 0; r < 16; r++) acc[i][j][r] = 0.f;

    // staging: thread t covers (row=t>>2, gseg=(t&3)^(row&3)), 16 bytes
    const int srow = tid >> 2;
    const int gseg = (tid & 3) ^ (srow & 3);
    const uint8_t* xa = txt_f8 + (size_t)(m0 + srow) * D_SZ + gseg * 16;
    const uint8_t* ya = Ybase + (size_t)srow * D_SZ + gseg * 16;
    uint8_t* lA = As + tid * 16;     // rows 0..63
    uint8_t* lB = Bs + tid * 16;

    for (int k0 = 0; k0 < D_SZ; k0 += 64) {
        gl_lds16(xa + k0, lA);
        gl_lds16(xa + 64 * D_SZ + k0, lA + 4096);
        gl_lds16(ya + k0, lB);
        gl_lds16(ya + 64 * D_SZ + k0, lB + 4096);
        __syncthreads();

        i32x8_t af[2], bf[2];
#pragma unroll
        for (int mt = 0; mt < 2; mt++) {
            const uint8_t* rp = As + (wm + 32 * mt + l31) * 64;
            int4 lo = *(const int4*)(rp + (((2 * kh + 0) ^ r3) * 16));
            int4 hi = *(const int4*)(rp + (((2 * kh + 1) ^ r3) * 16));
            af[mt][0] = lo.x; af[mt][1] = lo.y; af[mt][2] = lo.z; af[mt][3] = lo.w;
            af[mt][4] = hi.x; af[mt][5] = hi.y; af[mt][6] = hi.z; af[mt][7] = hi.w;
        }
#pragma unroll
        for (int nt = 0; nt < 2; nt++) {
            const uint8_t* rp = Bs + (wn + 32 * nt + l31) * 64;
            int4 lo = *(const int4*)(rp + (((2 * kh + 0) ^ r3) * 16));
            int4 hi = *(const int4*)(rp + (((2 * kh + 1) ^ r3) * 16));
            bf[nt][0] = lo.x; bf[nt][1] = lo.y; bf[nt][2] = lo.z; bf[nt][3] = lo.w;
            bf[nt][4] = hi.x; bf[nt][5] = hi.y; bf[nt][6] = hi.z; bf[nt][7] = hi.w;
        }

#pragma unroll
        for (int mt = 0; mt < 2; mt++)
#pragma unroll
            for (int nt = 0; nt < 2; nt++)
                acc[mt][nt] = __builtin_amdgcn_mfma_scale_f32_32x32x64_f8f6f4(
                    af[mt], bf[nt], acc[mt][nt], 0, 0, 0, E8M0_S, 0, E8M0_S);
        __syncthreads();
    }

    // Epilogue. 32x32 C/D: col = l31, row = (reg&3) + 8*(reg>>2) + 4*kh.
    float rowp[2][16];
#pragma unroll
    for (int mt = 0; mt < 2; mt++)
#pragma unroll
        for (int r = 0; r < 16; r++) rowp[mt][r] = 0.f;

#pragma unroll
    for (int nt = 0; nt < 2; nt++) {
        float colp = 0.f;
#pragma unroll
        for (int mt = 0; mt < 2; mt++) {
#pragma unroll
            for (int r = 0; r < 16; r++) {
                float e = __expf(acc[mt][nt][r] * INV_T);
                rowp[mt][r] += e;
                colp += e;
            }
        }
        if (q1) {
            colp += __shfl_xor(colp, 32);
            if (lane < 32)
                atomicAdd(&rs1[n0 + wn + 32 * nt + l31], colp);
        }
    }
    float* rtgt = q1 ? cs1 : rs2;
#pragma unroll
    for (int mt = 0; mt < 2; mt++) {
#pragma unroll
        for (int r = 0; r < 16; r++) {
            float v = rowp[mt][r];
            v += __shfl_xor(v, 1);
            v += __shfl_xor(v, 2);
            v += __shfl_xor(v, 4);
            v += __shfl_xor(v, 8);
            v += __shfl_xor(v, 16);
            if (l31 == 0) {
                int row = m0 + wm + 32 * mt + (r & 3) + 8 * (r >> 2) + 4 * kh;
                atomicAdd(&rtgt[row], v);
            }
        }
    }
}

// ---------------------------------------------------------------------------
// Finalize: logs of expsums + 20480 diagonal partials.
// ---------------------------------------------------------------------------
__global__ __launch_bounds__(256) void finalize_part(
    const float* __restrict__ rs1, const float* __restrict__ cs1,
    const float* __restrict__ rs2, const float* __restrict__ partials,
    float* __restrict__ out)
{
    float s1 = 0.f, s2 = 0.f, s3 = 0.f, pd = 0.f, pm = 0.f;
    for (int i = threadIdx.x; i < B_SZ; i += 256) {
        s1 += __logf(rs1[i]);
        s2 += __logf(cs1[i]);
        s3 += __logf(rs2[i]);
        pd += partials[i];
    }
    for (int i = threadIdx.x; i < B_SZ * K_SZ; i += 256)
        pm += partials[B_SZ + i];
#pragma unroll
    for (int d = 1; d < 64; d <<= 1) {
        s1 += __shfl_xor(s1, d); s2 += __shfl_xor(s2, d);
        s3 += __shfl_xor(s3, d); pd += __shfl_xor(pd, d);
        pm += __shfl_xor(pm, d);
    }
    __shared__ float red[5][4];
    const int w = threadIdx.x >> 6, lane = threadIdx.x & 63;
    if (lane == 0) {
        red[0][w] = s1; red[1][w] = s2; red[2][w] = s3;
        red[3][w] = pd; red[4][w] = pm;
    }
    __syncthreads();
    if (threadIdx.x == 0) {
        float S1 = red[0][0] + red[0][1] + red[0][2] + red[0][3];
        float S2 = red[1][0] + red[1][1] + red[1][2] + red[1][3];
        float S3 = red[2][0] + red[2][1] + red[2][2] + red[2][3];
        float DS = red[3][0] + red[3][1] + red[3][2] + red[3][3];
        float MS = red[4][0] + red[4][1] + red[4][2] + red[4][3];
        const float invB = 1.0f / (float)B_SZ;
        out[0] = 0.5f * (S1 + S2) * invB - DS * invB
               + 0.5f * (S3 * invB - MS / ((float)B_SZ * K_SZ));
    }
}

// ===========================================================================
// FALLBACK PATH (fp32->bf16 in-kernel, no workspace) ------------------------
// ===========================================================================
template <bool COLSUM>
__global__ __launch_bounds__(256) void gemm_expsum(
    const float* __restrict__ X, const float* __restrict__ Y,
    float* __restrict__ rowsum, float* __restrict__ colsum)
{
    __shared__ u16 As[128][32];
    __shared__ u16 Bs[128][32];
    const int m0 = blockIdx.y * 128, n0 = blockIdx.x * 128;
    const int tid = threadIdx.x, lane = tid & 63, w = tid >> 6;
    const int wm = (w & 1) * 64, wn = (w >> 1) * 64;
    const int lr = lane & 15, q = lane >> 4;
    f32x4_t acc[4][4];
#pragma unroll
    for (int i = 0; i < 4; i++)
#pragma unroll
        for (int j = 0; j < 4; j++) acc[i][j] = (f32x4_t){0.f, 0.f, 0.f, 0.f};
    const int kv = (tid & 7) * 4, r0 = tid >> 3;
    const float* xb = X + (size_t)(m0 + r0) * D_SZ + kv;
    const float* yb = Y + (size_t)(n0 + r0) * D_SZ + kv;
    for (int k0 = 0; k0 < D_SZ; k0 += 32) {
#pragma unroll
        for (int i = 0; i < 4; i++) {
            float4 a = *(const float4*)(xb + (size_t)(32 * i) * D_SZ + k0);
            float4 b = *(const float4*)(yb + (size_t)(32 * i) * D_SZ + k0);
            ushort4 ua, ub;
            ua.x = f2bf(a.x); ua.y = f2bf(a.y); ua.z = f2bf(a.z); ua.w = f2bf(a.w);
            ub.x = f2bf(b.x); ub.y = f2bf(b.y); ub.z = f2bf(b.z); ub.w = f2bf(b.w);
            *(ushort4*)&As[r0 + 32 * i][kv] = ua;
            *(ushort4*)&Bs[r0 + 32 * i][kv] = ub;
        }
        __syncthreads();
        bf16x8_t af[4], bfr[4];
#pragma unroll
        for (int mt = 0; mt < 4; mt++)
            af[mt] = *(const bf16x8_t*)&As[wm + 16 * mt + lr][8 * q];
#pragma unroll
        for (int nt = 0; nt < 4; nt++)
            bfr[nt] = *(const bf16x8_t*)&Bs[wn + 16 * nt + lr][8 * q];
#pragma unroll
        for (int mt = 0; mt < 4; mt++)
#pragma unroll
            for (int nt = 0; nt < 4; nt++)
                acc[mt][nt] = __builtin_amdgcn_mfma_f32_16x16x32_bf16(
                    af[mt], bfr[nt], acc[mt][nt], 0, 0, 0);
        __syncthreads();
    }
    float rowp[4][4];
#pragma unroll
    for (int mt = 0; mt < 4; mt++)
#pragma unroll
        for (int r = 0; r < 4; r++) rowp[mt][r] = 0.f;
#pragma unroll
    for (int nt = 0; nt < 4; nt++) {
        float colp = 0.f;
#pragma unroll
        for (int mt = 0; mt < 4; mt++)
#pragma unroll
            for (int r = 0; r < 4; r++) {
                float e = __expf(acc[mt][nt][r] * INV_T);
                colp += e; rowp[mt][r] += e;
            }
        if (COLSUM) {
            colp += __shfl_xor(colp, 16);
            colp += __shfl_xor(colp, 32);
            if (q == 0) atomicAdd(&colsum[n0 + wn + 16 * nt + lr], colp);
        }
    }
#pragma unroll
    for (int mt = 0; mt < 4; mt++)
#pragma unroll
        for (int r = 0; r < 4; r++) {
            float rp = rowp[mt][r];
            rp += __shfl_xor(rp, 1); rp += __shfl_xor(rp, 2);
            rp += __shfl_xor(rp, 4); rp += __shfl_xor(rp, 8);
            if (lr == 0) atomicAdd(&rowsum[m0 + wm + 16 * mt + 4 * q + r], rp);
        }
}

__global__ __launch_bounds__(256) void diag_kernel(
    const float* __restrict__ img, const float* __restrict__ txt,
    const float* __restrict__ other, float* __restrict__ dm)
{
    const int gw = blockIdx.x * 4 + (threadIdx.x >> 6);
    const int lane = threadIdx.x & 63;
    const float *pa, *pb; float* target;
    if (gw < B_SZ) {
        pa = img + (size_t)gw * D_SZ; pb = txt + (size_t)gw * D_SZ; target = dm;
    } else {
        const int g2 = gw - B_SZ;
        pa = other + (size_t)g2 * D_SZ; pb = txt + (size_t)(g2 >> 2) * D_SZ;
        target = dm + 1;
    }
    float s = 0.f;
#pragma unroll
    for (int j = 0; j < 4; j++) {
        float4 a = *(const float4*)(pa + 4 * (lane + 64 * j));
        float4 b = *(const float4*)(pb + 4 * (lane + 64 * j));
        s += a.x * b.x + a.y * b.y + a.z * b.z + a.w * b.w;
    }
#pragma unroll
    for (int d = 1; d < 64; d <<= 1) s += __shfl_xor(s, d);
    if (lane == 0) atomicAdd(target, s * INV_T);
}

__global__ __launch_bounds__(256) void finalize_atomic(
    const float* __restrict__ rs1, const float* __restrict__ cs1,
    const float* __restrict__ rs2, const float* __restrict__ dm,
    float* __restrict__ out)
{
    float s1 = 0.f, s2 = 0.f, s3 = 0.f;
    for (int i = threadIdx.x; i < B_SZ; i += 256) {
        s1 += __logf(rs1[i]); s2 += __logf(cs1[i]); s3 += __logf(rs2[i]);
    }
#pragma unroll
    for (int d = 1; d < 64; d <<= 1) {
        s1 += __shfl_xor(s1, d); s2 += __shfl_xor(s2, d); s3 += __shfl_xor(s3, d);
    }
    __shared__ float red[3][4];
    const int w = threadIdx.x >> 6, lane = threadIdx.x & 63;
    if (lane == 0) { red[0][w] = s1; red[1][w] = s2; red[2][w] = s3; }
    __syncthreads();
    if (threadIdx.x == 0) {
        float S1 = red[0][0] + red[0][1] + red[0][2] + red[0][3];
        float S2 = red[1][0] + red[1][1] + red[1][2] + red[1][3];
        float S3 = red[2][0] + red[2][1] + red[2][2] + red[2][3];
        const float invB = 1.0f / (float)B_SZ;
        out[0] = 0.5f * (S1 + S2) * invB - dm[0] * invB
               + 0.5f * (S3 * invB - dm[1] / ((float)B_SZ * K_SZ));
    }
}

// ===========================================================================
extern "C" void kernel_launch(void* const* d_in, const int* in_sizes, int n_in,
                              void* d_out, int out_size, void* d_ws, size_t ws_size,
                              hipStream_t stream) {
    const float* img   = (const float*)d_in[0];
    const float* txt   = (const float*)d_in[1];
    const float* other = (const float*)d_in[2];
    float* out = (float*)d_out;
    float* ws  = (float*)d_ws;

    float* rs1      = ws;                    // [4096]
    float* cs1      = ws + B_SZ;             // [4096]
    float* rs2      = ws + 2 * B_SZ;         // [4096]
    float* partials = ws + 3 * B_SZ;         // [20480] (main)
    float* dm       = ws + 3 * B_SZ;         // [2]     (fallback)

    const size_t hdr_floats = 3 * B_SZ + B_SZ + B_SZ * K_SZ;              // 32768
    const size_t f8_bytes   = (size_t)(2 * B_SZ + B_SZ * K_SZ) * D_SZ;    // 24 MB
    const size_t need = hdr_floats * sizeof(float) + f8_bytes;

    if (ws_size >= need) {
        uint8_t* img_f8 = (uint8_t*)(ws + hdr_floats);
        uint8_t* txt_f8 = img_f8 + (size_t)B_SZ * D_SZ;
        uint8_t* oth_f8 = txt_f8 + (size_t)B_SZ * D_SZ;

        hipMemsetAsync(d_ws, 0, 3 * B_SZ * sizeof(float), stream);
        hipLaunchKernelGGL(convert_diag_f8, dim3(2 * B_SZ + B_SZ * K_SZ), dim3(256),
                           0, stream, img, txt, other, img_f8, txt_f8, oth_f8,
                           partials);
        // fused W = txt . [img ; oth]^T : 160 x 32 blocks
        hipLaunchKernelGGL(gemm_expsum_mx,
                           dim3((B_SZ + B_SZ * K_SZ) / 128, B_SZ / 128), dim3(256),
                           0, stream, txt_f8, img_f8, oth_f8, rs1, cs1, rs2);
        hipLaunchKernelGGL(finalize_part, dim3(1), dim3(256), 0, stream,
                           rs1, cs1, rs2, partials, out);
    } else {
        hipMemsetAsync(d_ws, 0, (3 * B_SZ + 2) * sizeof(float), stream);
        hipLaunchKernelGGL((gemm_expsum<true>), dim3(B_SZ / 128, B_SZ / 128),
                           dim3(256), 0, stream, img, txt, rs1, cs1);
        hipLaunchKernelGGL((gemm_expsum<false>),
                           dim3(B_SZ * K_SZ / 128, B_SZ / 128), dim3(256), 0,
                           stream, txt, other, rs2, nullptr);
        hipLaunchKernelGGL(diag_kernel, dim3((B_SZ + B_SZ * K_SZ) / 4),
                           dim3(256), 0, stream, img, txt, other, dm);
        hipLaunchKernelGGL(finalize_atomic, dim3(1), dim3(256), 0, stream,
                           rs1, cs1, rs2, dm, out);
    }
}